// Round 3
// baseline (744.229 us; speedup 1.0000x reference)
//
#include <hip/hip_runtime.h>

// ---------------------------------------------------------------------------
// TernaryInvertedResidual on MI355X (gfx950) — R3
//
// vs R2: conv2 weights staged through double-buffered LDS (prefetched 1 tap
// ahead) instead of per-wave global loads (R2 was per-XCD-L2-BW bound and
// VGPR-starved at 252 regs / 0.8 blocks/CU). Operand swap (weights=MFMA-A,
// acts=MFMA-B) so C rows span co -> 8B vector stores in conv1/conv2
// epilogues. h2 linear; conv3 swizzles on staging source. Stats in 1 kernel.
// ---------------------------------------------------------------------------

typedef __bf16 bf16x8 __attribute__((ext_vector_type(8)));
typedef __bf16 bf16x4 __attribute__((ext_vector_type(4)));
typedef float  f32x4  __attribute__((ext_vector_type(4)));

#define EPSBN 1e-5f

// async global->LDS, 16B per lane; LDS dest = wave-uniform base + lane*16
__device__ __forceinline__ void glds16(const void* g, void* l) {
  __builtin_amdgcn_global_load_lds(
      (const __attribute__((address_space(1))) void*)g,
      (__attribute__((address_space(3))) void*)l, 16, 0, 0);
}

__device__ __forceinline__ __bf16 tern(float w, float delta) {
  float aw = fabsf(w);
  float q = (aw > delta) ? ((w > 0.0f) ? 1.0f : -1.0f) : 0.0f;
  return (__bf16)q;
}

// ---------------- ternarize stats (single kernel, deterministic) -----------
// block b handles tensor b: 0=w1(6144), 1=w2(331776), 2=w3(6144)
__global__ void stats_kernel(const float* __restrict__ w1, const float* __restrict__ w2,
                             const float* __restrict__ w3, float* __restrict__ stats) {
  __shared__ double red[256];
  __shared__ double red2[256];
  __shared__ float sdelta;
  int tix = blockIdx.x, tid = threadIdx.x;
  const float* w = (tix == 0) ? w1 : (tix == 1) ? w2 : w3;
  int len = (tix == 1) ? 331776 : 6144;

  double s = 0.0;
  for (int i = tid; i < len; i += 256) s += (double)fabsf(w[i]);
  red[tid] = s; __syncthreads();
  for (int off = 128; off > 0; off >>= 1) {
    if (tid < off) red[tid] += red[tid + off];
    __syncthreads();
  }
  if (tid == 0) sdelta = 0.7f * (float)(red[0] / (double)len);
  __syncthreads();
  float delta = sdelta;

  double s2 = 0.0, c2 = 0.0;
  for (int i = tid; i < len; i += 256) {
    float aw = fabsf(w[i]);
    if (aw > delta) { s2 += (double)aw; c2 += 1.0; }
  }
  red[tid] = s2; red2[tid] = c2; __syncthreads();
  for (int off = 128; off > 0; off >>= 1) {
    if (tid < off) { red[tid] += red[tid + off]; red2[tid] += red2[tid + off]; }
    __syncthreads();
  }
  if (tid == 0) {
    stats[tix * 2]     = delta;
    stats[tix * 2 + 1] = (float)(red[0] / fmax(red2[0], 1.0));
  }
}

// ---------------- weight pack + BN fold ------------------------------------
// w1p: [co=192][ci=32]  64B rows, 16B-chunk swizzled by ((co>>2)&3)
// w2p: [tap*6+cb][co=192][ci=32]  64B rows, 16B-chunk swizzled by ((co>>2)&3)
// w3p: [kc=3][co=32][ci=64]  128B rows, 16B-chunk swizzled by (co&7)
__global__ void pack_kernel(
    const float* __restrict__ w1, const float* __restrict__ w2, const float* __restrict__ w3,
    const float* __restrict__ g1, const float* __restrict__ b1, const float* __restrict__ m1, const float* __restrict__ v1,
    const float* __restrict__ g2, const float* __restrict__ b2, const float* __restrict__ m2, const float* __restrict__ v2,
    const float* __restrict__ g3, const float* __restrict__ b3, const float* __restrict__ m3, const float* __restrict__ v3,
    const float* __restrict__ stats,
    __bf16* __restrict__ w1p, __bf16* __restrict__ w2p, __bf16* __restrict__ w3p,
    float* __restrict__ sc1, float* __restrict__ sh1,
    float* __restrict__ sc2, float* __restrict__ sh2,
    float* __restrict__ sc3, float* __restrict__ sh3) {
  int idx = blockIdx.x * 256 + threadIdx.x;
  if (idx < 331776) {
    float delta2 = stats[2];
    int c = idx / 6144, rem = idx - c * 6144;
    int co = rem >> 5, r5 = rem & 31;
    int cp = r5 >> 3, lo = r5 & 7;
    int tap = c / 6, cb = c - tap * 6;
    int ci = ((cp ^ ((co >> 2) & 3)) << 3) | lo;   // source-side chunk swizzle
    int cifull = cb * 32 + ci;
    w2p[idx] = tern(w2[(co * 192 + cifull) * 9 + tap], delta2);
    return;
  }
  idx -= 331776;
  if (idx < 6144) {  // w1p, swizzled
    int co = idx >> 5, c = (idx >> 3) & 3, lo = idx & 7;
    int ci = ((c ^ ((co >> 2) & 3)) << 3) | lo;
    w1p[idx] = tern(w1[co * 32 + ci], stats[0]);
    return;
  }
  idx -= 6144;
  if (idx < 6144) {  // w3p, swizzled
    int kc = idx >> 11, rem = idx & 2047;
    int co = rem >> 6, c = (rem >> 3) & 7, lo = rem & 7;
    int ci = ((c ^ (co & 7)) << 3) | lo;
    w3p[idx] = tern(w3[co * 192 + kc * 64 + ci], stats[4]);
    return;
  }
  idx -= 6144;
  if (idx < 192) {
    float rs = rsqrtf(v1[idx] + EPSBN);
    sc1[idx] = g1[idx] * rs * stats[1];
    sh1[idx] = b1[idx] - m1[idx] * g1[idx] * rs;
    return;
  }
  idx -= 192;
  if (idx < 192) {
    float rs = rsqrtf(v2[idx] + EPSBN);
    sc2[idx] = g2[idx] * rs * stats[3];
    sh2[idx] = b2[idx] - m2[idx] * g2[idx] * rs;
    return;
  }
  idx -= 192;
  if (idx < 32) {
    float rs = rsqrtf(v3[idx] + EPSBN);
    sc3[idx] = g3[idx] * rs * stats[5];
    sh3[idx] = b3[idx] - m3[idx] * g3[idx] * rs;
  }
}

// ---------------- conv1: 1x1 (K=32) + fused border zero --------------------
// grid (112 h, 16 n), 256 threads (4 waves). A=weights (M=co 192), B=acts
// (N=w 112). Wave co-range 48 (3 frags) x 112 px (7 frags).
__global__ __launch_bounds__(256)
void conv1_kernel(const float* __restrict__ x, const __bf16* __restrict__ w1p,
                  const float* __restrict__ scale1, const float* __restrict__ shift1,
                  __bf16* __restrict__ h1p) {
  __shared__ __bf16 smA[112 * 32];  // acts [w][ci] 64B rows, chunk-swizzled
  __shared__ __bf16 smB[192 * 32];  // weights [co][ci] 64B rows, swizzle baked
  int tid = threadIdx.x, lane = tid & 63, wave = tid >> 6;
  int h = blockIdx.x, n = blockIdx.y;

  for (int t = wave; t < 12; t += 4)
    glds16((const char*)w1p + t * 1024 + lane * 16, (char*)smB + t * 1024);

  const float* xrow = x + (long)n * 401408 + h * 112;   // + ci*12544 + w
  for (int i = 0; i < 14; ++i) {
    int f = i * 256 + tid;            // 0..3583
    int ci = f / 112, w = f - ci * 112;
    int col = ((ci >> 3) ^ ((w >> 2) & 3));
    smA[w * 32 + (col << 3) + (ci & 7)] = (__bf16)xrow[ci * 12544 + w];
  }
  __syncthreads();

  int mrow = lane & 15, quad = lane >> 4;
  int col16 = (quad ^ ((mrow >> 2) & 3)) * 16;
  int c0 = wave * 48;

  bf16x8 aw[3], bv[7];
#pragma unroll
  for (int ic = 0; ic < 3; ++ic)
    aw[ic] = *(const bf16x8*)((const char*)smB + (c0 + ic * 16 + mrow) * 64 + col16);
#pragma unroll
  for (int jp = 0; jp < 7; ++jp)
    bv[jp] = *(const bf16x8*)((const char*)smA + (jp * 16 + mrow) * 64 + col16);

  f32x4 acc[7][3];
#pragma unroll
  for (int jp = 0; jp < 7; ++jp)
#pragma unroll
    for (int ic = 0; ic < 3; ++ic) acc[jp][ic] = (f32x4)0.0f;

#pragma unroll
  for (int jp = 0; jp < 7; ++jp)
#pragma unroll
    for (int ic = 0; ic < 3; ++ic)
      acc[jp][ic] = __builtin_amdgcn_mfma_f32_16x16x32_bf16(aw[ic], bv[jp], acc[jp][ic], 0, 0, 0);

  // epilogue: BN + ReLU6 -> padded NHWC interior (hp=h+1, wp=w+1), 8B stores
  __bf16* obase = h1p + ((long)(n * 114 + h + 1) * 114 + 1) * 192;
#pragma unroll
  for (int ic = 0; ic < 3; ++ic) {
    int co0 = c0 + ic * 16 + quad * 4;
    float4 sc = *(const float4*)(scale1 + co0);
    float4 sh = *(const float4*)(shift1 + co0);
#pragma unroll
    for (int jp = 0; jp < 7; ++jp) {
      int w = jp * 16 + mrow;
      bf16x4 o;
      o[0] = (__bf16)fminf(fmaxf(acc[jp][ic][0] * sc.x + sh.x, 0.0f), 6.0f);
      o[1] = (__bf16)fminf(fmaxf(acc[jp][ic][1] * sc.y + sh.y, 0.0f), 6.0f);
      o[2] = (__bf16)fminf(fmaxf(acc[jp][ic][2] * sc.z + sh.z, 0.0f), 6.0f);
      o[3] = (__bf16)fminf(fmaxf(acc[jp][ic][3] * sc.w + sh.w, 0.0f), 6.0f);
      *(bf16x4*)(obase + w * 192 + co0) = o;
    }
  }

  // fused border zeroing of h1p
  float4 z = make_float4(0.f, 0.f, 0.f, 0.f);
  if (tid < 48) {
    int px = (tid < 24) ? 0 : 113;
    int c8 = (tid < 24) ? tid : tid - 24;
    *(float4*)((char*)h1p + ((long)((n * 114 + h + 1) * 114 + px) * 384) + c8 * 16) = z;
  }
  if (h == 0) {
    for (int c = tid; c < 2736; c += 256)
      *(float4*)((char*)h1p + (long)(n * 114) * 114 * 384 + c * 16) = z;
  }
  if (h == 111) {
    for (int c = tid; c < 2736; c += 256)
      *(float4*)((char*)h1p + (long)(n * 114 + 113) * 114 * 384 + c * 16) = z;
  }
}

// ---------------- conv2: 3x3 (K=1728) implicit GEMM ------------------------
// grid (56 h-pairs, 16 n), 256 threads (4 waves).
// A=weights (M=co 192), B=acts (N=224 px). Wave tile co 96 (6) x px 112 (7).
// cb outer: A-window (4 rows x 114 x 32ci = 29184B) staged once per cb;
// weights double-buffered in LDS, prefetched one tap ahead.
__global__ __launch_bounds__(256, 2)
void conv2_kernel(const __bf16* __restrict__ h1p, const __bf16* __restrict__ w2p,
                  const float* __restrict__ scale2, const float* __restrict__ shift2,
                  __bf16* __restrict__ h2) {
  __shared__ __bf16 smA[456 * 32];      // act window, 64B rows, chunk-swizzled
  __shared__ __bf16 smB[2 * 192 * 32];  // weights dbuf, swizzle baked in w2p
  int tid = threadIdx.x, lane = tid & 63, wave = tid >> 6;
  int bh = blockIdx.x, n = blockIdx.y;
  int h0 = bh * 2;

  // A staging source offsets (bytes, + cb*64 at use); slot s = t*64+lane
  int aoff[8];
#pragma unroll
  for (int it = 0; it < 8; ++it) {
    int t = wave + it * 4;
    int s = t * 64 + lane;
    if (s < 1824) {
      int q = s >> 2, c = s & 3;
      int q_log = c ^ ((q >> 2) & 3);
      int prow = q / 114, pcol = q - prow * 114;
      aoff[it] = ((n * 114 + h0 + prow) * 114 + pcol) * 384 + q_log * 16;
    } else {
      aoff[it] = -1;
    }
  }

  int pg = wave >> 1, cg = wave & 1;
  int mrow = lane & 15, quad = lane >> 4;
  int col16 = (quad ^ ((mrow >> 2) & 3)) * 16;
  const char* h1b = (const char*)h1p;
  const char* w2b = (const char*)w2p;

  f32x4 acc[7][6];
#pragma unroll
  for (int jp = 0; jp < 7; ++jp)
#pragma unroll
    for (int ic = 0; ic < 6; ++ic) acc[jp][ic] = (f32x4)0.0f;

  for (int cb = 0; cb < 6; ++cb) {
    // stage A window + weights for tap 0 (buf 0)
#pragma unroll
    for (int it = 0; it < 8; ++it) {
      int t = wave + it * 4;
      if (aoff[it] >= 0)
        glds16(h1b + aoff[it] + cb * 64, (char*)smA + t * 1024);
    }
#pragma unroll
    for (int it = 0; it < 3; ++it) {
      int t = wave + it * 4;
      glds16(w2b + (long)cb * 12288 + t * 1024 + lane * 16, (char*)smB + t * 1024);
    }
    __syncthreads();

    for (int tap = 0; tap < 9; ++tap) {
      int cur = tap & 1;
      if (tap < 8) {   // prefetch next tap's weights into the other buffer
#pragma unroll
        for (int it = 0; it < 3; ++it) {
          int t = wave + it * 4;
          glds16(w2b + (long)((tap + 1) * 6 + cb) * 12288 + t * 1024 + lane * 16,
                 (char*)smB + (cur ^ 1) * 12288 + t * 1024);
        }
      }
      int dy = tap / 3, dx = tap - dy * 3;
      const char* bbuf = (const char*)smB + cur * 12288;
      bf16x8 aw[6];
#pragma unroll
      for (int ic = 0; ic < 6; ++ic)
        aw[ic] = *(const bf16x8*)(bbuf + (cg * 96 + ic * 16 + mrow) * 64 + col16);
      int base = (pg + dy) * 114 + dx;
#pragma unroll
      for (int jp = 0; jp < 7; ++jp) {
        int row = base + jp * 16 + mrow;
        bf16x8 av = *(const bf16x8*)((const char*)smA + row * 64 +
                                     ((quad ^ ((row >> 2) & 3)) * 16));
#pragma unroll
        for (int ic = 0; ic < 6; ++ic)
          acc[jp][ic] = __builtin_amdgcn_mfma_f32_16x16x32_bf16(aw[ic], av, acc[jp][ic], 0, 0, 0);
      }
      __syncthreads();
    }
  }

  // epilogue: BN + ReLU6 -> h2 linear NHWC [n][112][112][192] bf16, 8B stores
  int h = h0 + pg;
  __bf16* orow = h2 + (long)((n * 112 + h) * 112) * 192;
#pragma unroll
  for (int ic = 0; ic < 6; ++ic) {
    int co0 = cg * 96 + ic * 16 + quad * 4;
    float4 sc = *(const float4*)(scale2 + co0);
    float4 sh = *(const float4*)(shift2 + co0);
#pragma unroll
    for (int jp = 0; jp < 7; ++jp) {
      int w = jp * 16 + mrow;
      bf16x4 o;
      o[0] = (__bf16)fminf(fmaxf(acc[jp][ic][0] * sc.x + sh.x, 0.0f), 6.0f);
      o[1] = (__bf16)fminf(fmaxf(acc[jp][ic][1] * sc.y + sh.y, 0.0f), 6.0f);
      o[2] = (__bf16)fminf(fmaxf(acc[jp][ic][2] * sc.z + sh.z, 0.0f), 6.0f);
      o[3] = (__bf16)fminf(fmaxf(acc[jp][ic][3] * sc.w + sh.w, 0.0f), 6.0f);
      *(bf16x4*)(orow + w * 192 + co0) = o;
    }
  }
}

// ---------------- conv3: 1x1 (K=192) + residual ----------------------------
// grid (112 h, 16 n), 128 threads (2 waves). A=px(112), B=weights(32co).
// h2 is linear; bank swizzle applied on the staging SOURCE side.
__global__ __launch_bounds__(128)
void conv3_kernel(const __bf16* __restrict__ h2, const __bf16* __restrict__ w3p,
                  const float* __restrict__ scale3, const float* __restrict__ shift3,
                  const float* __restrict__ x, float* __restrict__ out) {
  __shared__ __bf16 smA[112 * 64];  // [w][ci64] 128B rows, chunk-swizzled
  __shared__ __bf16 smB[32 * 64];   // [co][ci64] 128B rows, swizzle baked
  int tid = threadIdx.x, lane = tid & 63, wv = tid >> 6;
  int h = blockIdx.x, n = blockIdx.y;
  int mrow = lane & 15, quad = lane >> 4;
  int swz7 = mrow & 7;

  const char* h2b = (const char*)h2 + (long)((n * 112 + h) * 112) * 384;
  f32x4 acc[7];
#pragma unroll
  for (int i = 0; i < 7; ++i) acc[i] = (f32x4)0.0f;

  for (int kc = 0; kc < 3; ++kc) {
    for (int t = wv; t < 18; t += 2) {
      if (t < 14) {
        int slot = t * 64 + lane;        // 0..895
        int w = slot >> 3, s = slot & 7;
        glds16(h2b + w * 384 + kc * 128 + (s ^ (w & 7)) * 16, (char*)smA + t * 1024);
      } else {
        glds16((const char*)w3p + kc * 4096 + (t - 14) * 1024 + lane * 16,
               (char*)smB + (t - 14) * 1024);
      }
    }
    __syncthreads();
    bf16x8 a[7][2], b[2];
#pragma unroll
    for (int ks = 0; ks < 2; ++ks) {
      int col = ((ks * 4 + quad) ^ swz7) * 16;
      b[ks] = *(const bf16x8*)((const char*)smB + (wv * 16 + mrow) * 128 + col);
#pragma unroll
      for (int i = 0; i < 7; ++i)
        a[i][ks] = *(const bf16x8*)((const char*)smA + (i * 16 + mrow) * 128 + col);
    }
    __syncthreads();
#pragma unroll
    for (int ks = 0; ks < 2; ++ks)
#pragma unroll
      for (int i = 0; i < 7; ++i)
        acc[i] = __builtin_amdgcn_mfma_f32_16x16x32_bf16(a[i][ks], b[ks], acc[i], 0, 0, 0);
  }

  // epilogue: BN (no act) + residual, fp32 float4 stores to NCHW
  int co = wv * 16 + mrow;
  float sc = scale3[co], sh = shift3[co];
  long obase = ((long)(n * 32 + co) * 112 + h) * 112;
  const float* xb = x + obase;
  float* ob = out + obase;
#pragma unroll
  for (int i = 0; i < 7; ++i) {
    int w0 = i * 16 + quad * 4;
    float4 xv = *(const float4*)(xb + w0);
    float4 o;
    o.x = acc[i][0] * sc + sh + xv.x;
    o.y = acc[i][1] * sc + sh + xv.y;
    o.z = acc[i][2] * sc + sh + xv.z;
    o.w = acc[i][3] * sc + sh + xv.w;
    *(float4*)(ob + w0) = o;
  }
}

// ---------------- launch ---------------------------------------------------
extern "C" void kernel_launch(void* const* d_in, const int* in_sizes, int n_in,
                              void* d_out, int out_size, void* d_ws, size_t ws_size,
                              hipStream_t stream) {
  const float* x  = (const float*)d_in[0];
  const float* w1 = (const float*)d_in[1];
  const float* g1 = (const float*)d_in[2];
  const float* b1 = (const float*)d_in[3];
  const float* m1 = (const float*)d_in[4];
  const float* v1 = (const float*)d_in[5];
  const float* w2 = (const float*)d_in[6];
  const float* g2 = (const float*)d_in[7];
  const float* b2 = (const float*)d_in[8];
  const float* m2 = (const float*)d_in[9];
  const float* v2 = (const float*)d_in[10];
  const float* w3 = (const float*)d_in[11];
  const float* g3 = (const float*)d_in[12];
  const float* b3 = (const float*)d_in[13];
  const float* m3 = (const float*)d_in[14];
  const float* v3 = (const float*)d_in[15];
  float* out = (float*)d_out;

  char* ws = (char*)d_ws;
  float* stats = (float*)ws;                  // 6 floats
  float* sc1 = (float*)(ws + 2560);
  float* sh1 = (float*)(ws + 3328);
  float* sc2 = (float*)(ws + 4096);
  float* sh2 = (float*)(ws + 4864);
  float* sc3 = (float*)(ws + 5632);
  float* sh3 = (float*)(ws + 5760);
  __bf16* w1p = (__bf16*)(ws + 8192);         // 12288 B
  __bf16* w3p = (__bf16*)(ws + 20480);        // 12288 B
  __bf16* w2p = (__bf16*)(ws + 32768);        // 663552 B
  __bf16* h1p = (__bf16*)(ws + (1 << 20));                 // 79847424 B (padded NHWC)
  __bf16* h2  = (__bf16*)(ws + (1 << 20) + 79847424);      // 77070336 B (linear NHWC)

  hipLaunchKernelGGL(stats_kernel, dim3(3), dim3(256), 0, stream, w1, w2, w3, stats);
  hipLaunchKernelGGL(pack_kernel, dim3(1346), dim3(256), 0, stream, w1, w2, w3,
                     g1, b1, m1, v1, g2, b2, m2, v2, g3, b3, m3, v3, stats,
                     w1p, w2p, w3p, sc1, sh1, sc2, sh2, sc3, sh3);
  hipLaunchKernelGGL(conv1_kernel, dim3(112, 16), dim3(256), 0, stream, x, w1p, sc1, sh1, h1p);
  hipLaunchKernelGGL(conv2_kernel, dim3(56, 16), dim3(256), 0, stream, h1p, w2p, sc2, sh2, h2);
  hipLaunchKernelGGL(conv3_kernel, dim3(112, 16), dim3(128), 0, stream, h2, w3p, sc3, sh3, x, out);
}

// Round 4
// 300.629 us; speedup vs baseline: 2.4756x; 2.4756x over previous
//
#include <hip/hip_runtime.h>

// ---------------------------------------------------------------------------
// TernaryInvertedResidual on MI355X (gfx950) — R4
//
// vs R3: stats computation restored to the parallel 3-pass scheme (96 blocks
// per pass). R3's fused single-kernel stats ran 3 blocks total -> the w2
// reduction serialized on one CU at ~500us (Occupancy 0.05%). Convs unchanged
// from R3 for clean attribution of the conv2 weight-dbuf restructure.
// ---------------------------------------------------------------------------

typedef __bf16 bf16x8 __attribute__((ext_vector_type(8)));
typedef __bf16 bf16x4 __attribute__((ext_vector_type(4)));
typedef float  f32x4  __attribute__((ext_vector_type(4)));

#define EPSBN 1e-5f

// async global->LDS, 16B per lane; LDS dest = wave-uniform base + lane*16
__device__ __forceinline__ void glds16(const void* g, void* l) {
  __builtin_amdgcn_global_load_lds(
      (const __attribute__((address_space(1))) void*)g,
      (__attribute__((address_space(3))) void*)l, 16, 0, 0);
}

__device__ __forceinline__ __bf16 tern(float w, float delta) {
  float aw = fabsf(w);
  float q = (aw > delta) ? ((w > 0.0f) ? 1.0f : -1.0f) : 0.0f;
  return (__bf16)q;
}

// ---------------- ternarize stats (deterministic, no atomics) --------------
// tensor index: 0=w1 (6144), 1=w2 (331776), 2=w3 (6144)

__global__ void stats_pass1(const float* __restrict__ w1, const float* __restrict__ w2,
                            const float* __restrict__ w3, double* __restrict__ pa) {
  __shared__ double red[256];
  int b = blockIdx.x, tid = threadIdx.x;
  int tix = b >> 5, slice = b & 31;
  const float* w = (tix == 0) ? w1 : (tix == 1) ? w2 : w3;
  int len = (tix == 1) ? 331776 : 6144;
  int per = len >> 5;
  int start = slice * per, end = start + per;
  double s = 0.0;
  for (int i = start + tid; i < end; i += 256) s += (double)fabsf(w[i]);
  red[tid] = s; __syncthreads();
  for (int off = 128; off > 0; off >>= 1) {
    if (tid < off) red[tid] += red[tid + off];
    __syncthreads();
  }
  if (tid == 0) pa[b] = red[0];
}

__global__ void stats_pass2(const float* __restrict__ w1, const float* __restrict__ w2,
                            const float* __restrict__ w3, const double* __restrict__ pa,
                            double* __restrict__ ps2, double* __restrict__ pc2) {
  __shared__ double red[256];
  int b = blockIdx.x, tid = threadIdx.x;
  int tix = b >> 5, slice = b & 31;
  const float* w = (tix == 0) ? w1 : (tix == 1) ? w2 : w3;
  int len = (tix == 1) ? 331776 : 6144;
  double tot = 0.0;
  for (int k = 0; k < 32; ++k) tot += pa[tix * 32 + k];
  float delta = 0.7f * (float)(tot / (double)len);
  int per = len >> 5;
  int start = slice * per, end = start + per;
  double s2 = 0.0, c2 = 0.0;
  for (int i = start + tid; i < end; i += 256) {
    float aw = fabsf(w[i]);
    if (aw > delta) { s2 += (double)aw; c2 += 1.0; }
  }
  red[tid] = s2; __syncthreads();
  for (int off = 128; off > 0; off >>= 1) {
    if (tid < off) red[tid] += red[tid + off];
    __syncthreads();
  }
  if (tid == 0) ps2[b] = red[0];
  __syncthreads();
  red[tid] = c2; __syncthreads();
  for (int off = 128; off > 0; off >>= 1) {
    if (tid < off) red[tid] += red[tid + off];
    __syncthreads();
  }
  if (tid == 0) pc2[b] = red[0];
}

__global__ void stats_pass3(const double* __restrict__ pa, const double* __restrict__ ps2,
                            const double* __restrict__ pc2, float* __restrict__ stats) {
  int tix = blockIdx.x;
  if (threadIdx.x != 0) return;
  double tot = 0.0, s2 = 0.0, c2 = 0.0;
  for (int k = 0; k < 32; ++k) {
    tot += pa[tix * 32 + k];
    s2  += ps2[tix * 32 + k];
    c2  += pc2[tix * 32 + k];
  }
  int len = (tix == 1) ? 331776 : 6144;
  stats[tix * 2]     = 0.7f * (float)(tot / (double)len);  // delta
  stats[tix * 2 + 1] = (float)(s2 / fmax(c2, 1.0));        // alpha
}

// ---------------- weight pack + BN fold ------------------------------------
// w1p: [co=192][ci=32]  64B rows, 16B-chunk swizzled by ((co>>2)&3)
// w2p: [tap*6+cb][co=192][ci=32]  64B rows, 16B-chunk swizzled by ((co>>2)&3)
// w3p: [kc=3][co=32][ci=64]  128B rows, 16B-chunk swizzled by (co&7)
__global__ void pack_kernel(
    const float* __restrict__ w1, const float* __restrict__ w2, const float* __restrict__ w3,
    const float* __restrict__ g1, const float* __restrict__ b1, const float* __restrict__ m1, const float* __restrict__ v1,
    const float* __restrict__ g2, const float* __restrict__ b2, const float* __restrict__ m2, const float* __restrict__ v2,
    const float* __restrict__ g3, const float* __restrict__ b3, const float* __restrict__ m3, const float* __restrict__ v3,
    const float* __restrict__ stats,
    __bf16* __restrict__ w1p, __bf16* __restrict__ w2p, __bf16* __restrict__ w3p,
    float* __restrict__ sc1, float* __restrict__ sh1,
    float* __restrict__ sc2, float* __restrict__ sh2,
    float* __restrict__ sc3, float* __restrict__ sh3) {
  int idx = blockIdx.x * 256 + threadIdx.x;
  if (idx < 331776) {
    float delta2 = stats[2];
    int c = idx / 6144, rem = idx - c * 6144;
    int co = rem >> 5, r5 = rem & 31;
    int cp = r5 >> 3, lo = r5 & 7;
    int tap = c / 6, cb = c - tap * 6;
    int ci = ((cp ^ ((co >> 2) & 3)) << 3) | lo;   // source-side chunk swizzle
    int cifull = cb * 32 + ci;
    w2p[idx] = tern(w2[(co * 192 + cifull) * 9 + tap], delta2);
    return;
  }
  idx -= 331776;
  if (idx < 6144) {  // w1p, swizzled
    int co = idx >> 5, c = (idx >> 3) & 3, lo = idx & 7;
    int ci = ((c ^ ((co >> 2) & 3)) << 3) | lo;
    w1p[idx] = tern(w1[co * 32 + ci], stats[0]);
    return;
  }
  idx -= 6144;
  if (idx < 6144) {  // w3p, swizzled
    int kc = idx >> 11, rem = idx & 2047;
    int co = rem >> 6, c = (rem >> 3) & 7, lo = rem & 7;
    int ci = ((c ^ (co & 7)) << 3) | lo;
    w3p[idx] = tern(w3[co * 192 + kc * 64 + ci], stats[4]);
    return;
  }
  idx -= 6144;
  if (idx < 192) {
    float rs = rsqrtf(v1[idx] + EPSBN);
    sc1[idx] = g1[idx] * rs * stats[1];
    sh1[idx] = b1[idx] - m1[idx] * g1[idx] * rs;
    return;
  }
  idx -= 192;
  if (idx < 192) {
    float rs = rsqrtf(v2[idx] + EPSBN);
    sc2[idx] = g2[idx] * rs * stats[3];
    sh2[idx] = b2[idx] - m2[idx] * g2[idx] * rs;
    return;
  }
  idx -= 192;
  if (idx < 32) {
    float rs = rsqrtf(v3[idx] + EPSBN);
    sc3[idx] = g3[idx] * rs * stats[5];
    sh3[idx] = b3[idx] - m3[idx] * g3[idx] * rs;
  }
}

// ---------------- conv1: 1x1 (K=32) + fused border zero --------------------
// grid (112 h, 16 n), 256 threads (4 waves). A=weights (M=co 192), B=acts
// (N=w 112). Wave co-range 48 (3 frags) x 112 px (7 frags).
__global__ __launch_bounds__(256)
void conv1_kernel(const float* __restrict__ x, const __bf16* __restrict__ w1p,
                  const float* __restrict__ scale1, const float* __restrict__ shift1,
                  __bf16* __restrict__ h1p) {
  __shared__ __bf16 smA[112 * 32];  // acts [w][ci] 64B rows, chunk-swizzled
  __shared__ __bf16 smB[192 * 32];  // weights [co][ci] 64B rows, swizzle baked
  int tid = threadIdx.x, lane = tid & 63, wave = tid >> 6;
  int h = blockIdx.x, n = blockIdx.y;

  for (int t = wave; t < 12; t += 4)
    glds16((const char*)w1p + t * 1024 + lane * 16, (char*)smB + t * 1024);

  const float* xrow = x + (long)n * 401408 + h * 112;   // + ci*12544 + w
  for (int i = 0; i < 14; ++i) {
    int f = i * 256 + tid;            // 0..3583
    int ci = f / 112, w = f - ci * 112;
    int col = ((ci >> 3) ^ ((w >> 2) & 3));
    smA[w * 32 + (col << 3) + (ci & 7)] = (__bf16)xrow[ci * 12544 + w];
  }
  __syncthreads();

  int mrow = lane & 15, quad = lane >> 4;
  int col16 = (quad ^ ((mrow >> 2) & 3)) * 16;
  int c0 = wave * 48;

  bf16x8 aw[3], bv[7];
#pragma unroll
  for (int ic = 0; ic < 3; ++ic)
    aw[ic] = *(const bf16x8*)((const char*)smB + (c0 + ic * 16 + mrow) * 64 + col16);
#pragma unroll
  for (int jp = 0; jp < 7; ++jp)
    bv[jp] = *(const bf16x8*)((const char*)smA + (jp * 16 + mrow) * 64 + col16);

  f32x4 acc[7][3];
#pragma unroll
  for (int jp = 0; jp < 7; ++jp)
#pragma unroll
    for (int ic = 0; ic < 3; ++ic) acc[jp][ic] = (f32x4)0.0f;

#pragma unroll
  for (int jp = 0; jp < 7; ++jp)
#pragma unroll
    for (int ic = 0; ic < 3; ++ic)
      acc[jp][ic] = __builtin_amdgcn_mfma_f32_16x16x32_bf16(aw[ic], bv[jp], acc[jp][ic], 0, 0, 0);

  // epilogue: BN + ReLU6 -> padded NHWC interior (hp=h+1, wp=w+1), 8B stores
  __bf16* obase = h1p + ((long)(n * 114 + h + 1) * 114 + 1) * 192;
#pragma unroll
  for (int ic = 0; ic < 3; ++ic) {
    int co0 = c0 + ic * 16 + quad * 4;
    float4 sc = *(const float4*)(scale1 + co0);
    float4 sh = *(const float4*)(shift1 + co0);
#pragma unroll
    for (int jp = 0; jp < 7; ++jp) {
      int w = jp * 16 + mrow;
      bf16x4 o;
      o[0] = (__bf16)fminf(fmaxf(acc[jp][ic][0] * sc.x + sh.x, 0.0f), 6.0f);
      o[1] = (__bf16)fminf(fmaxf(acc[jp][ic][1] * sc.y + sh.y, 0.0f), 6.0f);
      o[2] = (__bf16)fminf(fmaxf(acc[jp][ic][2] * sc.z + sh.z, 0.0f), 6.0f);
      o[3] = (__bf16)fminf(fmaxf(acc[jp][ic][3] * sc.w + sh.w, 0.0f), 6.0f);
      *(bf16x4*)(obase + w * 192 + co0) = o;
    }
  }

  // fused border zeroing of h1p
  float4 z = make_float4(0.f, 0.f, 0.f, 0.f);
  if (tid < 48) {
    int px = (tid < 24) ? 0 : 113;
    int c8 = (tid < 24) ? tid : tid - 24;
    *(float4*)((char*)h1p + ((long)((n * 114 + h + 1) * 114 + px) * 384) + c8 * 16) = z;
  }
  if (h == 0) {
    for (int c = tid; c < 2736; c += 256)
      *(float4*)((char*)h1p + (long)(n * 114) * 114 * 384 + c * 16) = z;
  }
  if (h == 111) {
    for (int c = tid; c < 2736; c += 256)
      *(float4*)((char*)h1p + (long)(n * 114 + 113) * 114 * 384 + c * 16) = z;
  }
}

// ---------------- conv2: 3x3 (K=1728) implicit GEMM ------------------------
// grid (56 h-pairs, 16 n), 256 threads (4 waves).
// A=weights (M=co 192), B=acts (N=224 px). Wave tile co 96 (6) x px 112 (7).
// cb outer: A-window (4 rows x 114 x 32ci = 29184B) staged once per cb;
// weights double-buffered in LDS, prefetched one tap ahead.
__global__ __launch_bounds__(256, 2)
void conv2_kernel(const __bf16* __restrict__ h1p, const __bf16* __restrict__ w2p,
                  const float* __restrict__ scale2, const float* __restrict__ shift2,
                  __bf16* __restrict__ h2) {
  __shared__ __bf16 smA[456 * 32];      // act window, 64B rows, chunk-swizzled
  __shared__ __bf16 smB[2 * 192 * 32];  // weights dbuf, swizzle baked in w2p
  int tid = threadIdx.x, lane = tid & 63, wave = tid >> 6;
  int bh = blockIdx.x, n = blockIdx.y;
  int h0 = bh * 2;

  // A staging source offsets (bytes, + cb*64 at use); slot s = t*64+lane
  int aoff[8];
#pragma unroll
  for (int it = 0; it < 8; ++it) {
    int t = wave + it * 4;
    int s = t * 64 + lane;
    if (s < 1824) {
      int q = s >> 2, c = s & 3;
      int q_log = c ^ ((q >> 2) & 3);
      int prow = q / 114, pcol = q - prow * 114;
      aoff[it] = ((n * 114 + h0 + prow) * 114 + pcol) * 384 + q_log * 16;
    } else {
      aoff[it] = -1;
    }
  }

  int pg = wave >> 1, cg = wave & 1;
  int mrow = lane & 15, quad = lane >> 4;
  int col16 = (quad ^ ((mrow >> 2) & 3)) * 16;
  const char* h1b = (const char*)h1p;
  const char* w2b = (const char*)w2p;

  f32x4 acc[7][6];
#pragma unroll
  for (int jp = 0; jp < 7; ++jp)
#pragma unroll
    for (int ic = 0; ic < 6; ++ic) acc[jp][ic] = (f32x4)0.0f;

  for (int cb = 0; cb < 6; ++cb) {
    // stage A window + weights for tap 0 (buf 0)
#pragma unroll
    for (int it = 0; it < 8; ++it) {
      int t = wave + it * 4;
      if (aoff[it] >= 0)
        glds16(h1b + aoff[it] + cb * 64, (char*)smA + t * 1024);
    }
#pragma unroll
    for (int it = 0; it < 3; ++it) {
      int t = wave + it * 4;
      glds16(w2b + (long)cb * 12288 + t * 1024 + lane * 16, (char*)smB + t * 1024);
    }
    __syncthreads();

    for (int tap = 0; tap < 9; ++tap) {
      int cur = tap & 1;
      if (tap < 8) {   // prefetch next tap's weights into the other buffer
#pragma unroll
        for (int it = 0; it < 3; ++it) {
          int t = wave + it * 4;
          glds16(w2b + (long)((tap + 1) * 6 + cb) * 12288 + t * 1024 + lane * 16,
                 (char*)smB + (cur ^ 1) * 12288 + t * 1024);
        }
      }
      int dy = tap / 3, dx = tap - dy * 3;
      const char* bbuf = (const char*)smB + cur * 12288;
      bf16x8 aw[6];
#pragma unroll
      for (int ic = 0; ic < 6; ++ic)
        aw[ic] = *(const bf16x8*)(bbuf + (cg * 96 + ic * 16 + mrow) * 64 + col16);
      int base = (pg + dy) * 114 + dx;
#pragma unroll
      for (int jp = 0; jp < 7; ++jp) {
        int row = base + jp * 16 + mrow;
        bf16x8 av = *(const bf16x8*)((const char*)smA + row * 64 +
                                     ((quad ^ ((row >> 2) & 3)) * 16));
#pragma unroll
        for (int ic = 0; ic < 6; ++ic)
          acc[jp][ic] = __builtin_amdgcn_mfma_f32_16x16x32_bf16(aw[ic], av, acc[jp][ic], 0, 0, 0);
      }
      __syncthreads();
    }
  }

  // epilogue: BN + ReLU6 -> h2 linear NHWC [n][112][112][192] bf16, 8B stores
  int h = h0 + pg;
  __bf16* orow = h2 + (long)((n * 112 + h) * 112) * 192;
#pragma unroll
  for (int ic = 0; ic < 6; ++ic) {
    int co0 = cg * 96 + ic * 16 + quad * 4;
    float4 sc = *(const float4*)(scale2 + co0);
    float4 sh = *(const float4*)(shift2 + co0);
#pragma unroll
    for (int jp = 0; jp < 7; ++jp) {
      int w = jp * 16 + mrow;
      bf16x4 o;
      o[0] = (__bf16)fminf(fmaxf(acc[jp][ic][0] * sc.x + sh.x, 0.0f), 6.0f);
      o[1] = (__bf16)fminf(fmaxf(acc[jp][ic][1] * sc.y + sh.y, 0.0f), 6.0f);
      o[2] = (__bf16)fminf(fmaxf(acc[jp][ic][2] * sc.z + sh.z, 0.0f), 6.0f);
      o[3] = (__bf16)fminf(fmaxf(acc[jp][ic][3] * sc.w + sh.w, 0.0f), 6.0f);
      *(bf16x4*)(orow + w * 192 + co0) = o;
    }
  }
}

// ---------------- conv3: 1x1 (K=192) + residual ----------------------------
// grid (112 h, 16 n), 128 threads (2 waves). A=px(112), B=weights(32co).
// h2 is linear; bank swizzle applied on the staging SOURCE side.
__global__ __launch_bounds__(128)
void conv3_kernel(const __bf16* __restrict__ h2, const __bf16* __restrict__ w3p,
                  const float* __restrict__ scale3, const float* __restrict__ shift3,
                  const float* __restrict__ x, float* __restrict__ out) {
  __shared__ __bf16 smA[112 * 64];  // [w][ci64] 128B rows, chunk-swizzled
  __shared__ __bf16 smB[32 * 64];   // [co][ci64] 128B rows, swizzle baked
  int tid = threadIdx.x, lane = tid & 63, wv = tid >> 6;
  int h = blockIdx.x, n = blockIdx.y;
  int mrow = lane & 15, quad = lane >> 4;
  int swz7 = mrow & 7;

  const char* h2b = (const char*)h2 + (long)((n * 112 + h) * 112) * 384;
  f32x4 acc[7];
#pragma unroll
  for (int i = 0; i < 7; ++i) acc[i] = (f32x4)0.0f;

  for (int kc = 0; kc < 3; ++kc) {
    for (int t = wv; t < 18; t += 2) {
      if (t < 14) {
        int slot = t * 64 + lane;        // 0..895
        int w = slot >> 3, s = slot & 7;
        glds16(h2b + w * 384 + kc * 128 + (s ^ (w & 7)) * 16, (char*)smA + t * 1024);
      } else {
        glds16((const char*)w3p + kc * 4096 + (t - 14) * 1024 + lane * 16,
               (char*)smB + (t - 14) * 1024);
      }
    }
    __syncthreads();
    bf16x8 a[7][2], b[2];
#pragma unroll
    for (int ks = 0; ks < 2; ++ks) {
      int col = ((ks * 4 + quad) ^ swz7) * 16;
      b[ks] = *(const bf16x8*)((const char*)smB + (wv * 16 + mrow) * 128 + col);
#pragma unroll
      for (int i = 0; i < 7; ++i)
        a[i][ks] = *(const bf16x8*)((const char*)smA + (i * 16 + mrow) * 128 + col);
    }
    __syncthreads();
#pragma unroll
    for (int ks = 0; ks < 2; ++ks)
#pragma unroll
      for (int i = 0; i < 7; ++i)
        acc[i] = __builtin_amdgcn_mfma_f32_16x16x32_bf16(a[i][ks], b[ks], acc[i], 0, 0, 0);
  }

  // epilogue: BN (no act) + residual, fp32 float4 stores to NCHW
  int co = wv * 16 + mrow;
  float sc = scale3[co], sh = shift3[co];
  long obase = ((long)(n * 32 + co) * 112 + h) * 112;
  const float* xb = x + obase;
  float* ob = out + obase;
#pragma unroll
  for (int i = 0; i < 7; ++i) {
    int w0 = i * 16 + quad * 4;
    float4 xv = *(const float4*)(xb + w0);
    float4 o;
    o.x = acc[i][0] * sc + sh + xv.x;
    o.y = acc[i][1] * sc + sh + xv.y;
    o.z = acc[i][2] * sc + sh + xv.z;
    o.w = acc[i][3] * sc + sh + xv.w;
    *(float4*)(ob + w0) = o;
  }
}

// ---------------- launch ---------------------------------------------------
extern "C" void kernel_launch(void* const* d_in, const int* in_sizes, int n_in,
                              void* d_out, int out_size, void* d_ws, size_t ws_size,
                              hipStream_t stream) {
  const float* x  = (const float*)d_in[0];
  const float* w1 = (const float*)d_in[1];
  const float* g1 = (const float*)d_in[2];
  const float* b1 = (const float*)d_in[3];
  const float* m1 = (const float*)d_in[4];
  const float* v1 = (const float*)d_in[5];
  const float* w2 = (const float*)d_in[6];
  const float* g2 = (const float*)d_in[7];
  const float* b2 = (const float*)d_in[8];
  const float* m2 = (const float*)d_in[9];
  const float* v2 = (const float*)d_in[10];
  const float* w3 = (const float*)d_in[11];
  const float* g3 = (const float*)d_in[12];
  const float* b3 = (const float*)d_in[13];
  const float* m3 = (const float*)d_in[14];
  const float* v3 = (const float*)d_in[15];
  float* out = (float*)d_out;

  char* ws = (char*)d_ws;
  float*  stats = (float*)ws;                 // 6 floats
  double* pa    = (double*)(ws + 256);        // 96 doubles
  double* ps2   = (double*)(ws + 1024);
  double* pc2   = (double*)(ws + 1792);
  float* sc1 = (float*)(ws + 2560);
  float* sh1 = (float*)(ws + 3328);
  float* sc2 = (float*)(ws + 4096);
  float* sh2 = (float*)(ws + 4864);
  float* sc3 = (float*)(ws + 5632);
  float* sh3 = (float*)(ws + 5760);
  __bf16* w1p = (__bf16*)(ws + 8192);         // 12288 B
  __bf16* w3p = (__bf16*)(ws + 20480);        // 12288 B
  __bf16* w2p = (__bf16*)(ws + 32768);        // 663552 B
  __bf16* h1p = (__bf16*)(ws + (1 << 20));                 // 79847424 B (padded NHWC)
  __bf16* h2  = (__bf16*)(ws + (1 << 20) + 79847424);      // 77070336 B (linear NHWC)

  hipLaunchKernelGGL(stats_pass1, dim3(96), dim3(256), 0, stream, w1, w2, w3, pa);
  hipLaunchKernelGGL(stats_pass2, dim3(96), dim3(256), 0, stream, w1, w2, w3, pa, ps2, pc2);
  hipLaunchKernelGGL(stats_pass3, dim3(3), dim3(64), 0, stream, pa, ps2, pc2, stats);
  hipLaunchKernelGGL(pack_kernel, dim3(1346), dim3(256), 0, stream, w1, w2, w3,
                     g1, b1, m1, v1, g2, b2, m2, v2, g3, b3, m3, v3, stats,
                     w1p, w2p, w3p, sc1, sh1, sc2, sh2, sc3, sh3);
  hipLaunchKernelGGL(conv1_kernel, dim3(112, 16), dim3(256), 0, stream, x, w1p, sc1, sh1, h1p);
  hipLaunchKernelGGL(conv2_kernel, dim3(56, 16), dim3(256), 0, stream, h1p, w2p, sc2, sh2, h2);
  hipLaunchKernelGGL(conv3_kernel, dim3(112, 16), dim3(128), 0, stream, h2, w3p, sc3, sh3, x, out);
}